// Round 6
// baseline (2142.796 us; speedup 1.0000x reference)
//
#include <hip/hip_runtime.h>
#include <cstdio>

typedef unsigned short u16;
typedef unsigned int u32;
typedef unsigned long long u64;
typedef __attribute__((ext_vector_type(8))) short bf16x8;   // 8 x bf16 (4 VGPRs)
typedef __attribute__((ext_vector_type(4))) float f32x4;

#define NWG 128
#define SENT16 0x7F80u          // +inf bf16: impossible h value (|h|<1, h0 finite)
#define SENT32 0x7F807F80u

__device__ inline u16 f2bf(float x) {
  union { float f; unsigned u; } v; v.f = x;
  unsigned r = v.u + 0x7FFFu + ((v.u >> 16) & 1u);   // RNE
  return (u16)(r >> 16);
}
__device__ inline float sigm(float x) { return 1.0f / (1.0f + __expf(-x)); }
__device__ inline float tanh_fast(float x) { return 1.0f - 2.0f / (__expf(2.0f * x) + 1.0f); }
// producer stores whole u32 words atomically -> checking the low bf16 of each u32 suffices
__device__ inline bool badw(u64 v) {
  return (((u32)v & 0xffffu) == SENT16) | (((u32)(v >> 32) & 0xffffu) == SENT16);
}

// ---------------- fp32 -> bf16 convert (vectorized) ----------------
__global__ __launch_bounds__(256) void k_convert(const float* __restrict__ in,
                                                 u16* __restrict__ out, int n4) {
  int i = blockIdx.x * blockDim.x + threadIdx.x;
  int stride = gridDim.x * blockDim.x;
  const float4* in4 = (const float4*)in;
  ushort4* out4 = (ushort4*)out;
  for (; i < n4; i += stride) {
    float4 v = in4[i];
    ushort4 o; o.x = f2bf(v.x); o.y = f2bf(v.y); o.z = f2bf(v.z); o.w = f2bf(v.w);
    out4[i] = o;
  }
}

// fill h step-sequence buffers with the sentinel pattern
__global__ __launch_bounds__(256) void k_clear(uint4* __restrict__ p, int n) {
  int i = blockIdx.x * blockDim.x + threadIdx.x;
  int stride = gridDim.x * blockDim.x;
  uint4 s = make_uint4(SENT32, SENT32, SENT32, SENT32);
  for (; i < n; i += stride) p[i] = s;
}

// h0 -> step slot 0 (bf16); runs AFTER k_clear
__global__ __launch_bounds__(256) void k_init_h(const float* __restrict__ h0,
                                                u16* __restrict__ hseq) {
  int i = blockIdx.x * blockDim.x + threadIdx.x;
  if (i < 32768) hseq[i] = f2bf(h0[i]);
}

// [R][C] fp32 -> [C][R] bf16 (tiled transpose)
__global__ __launch_bounds__(256) void k_transpose(const float* __restrict__ in,
                                                   u16* __restrict__ out, int R, int C) {
  __shared__ u16 tile[32][33];
  int tx = threadIdx.x & 31, ty = threadIdx.x >> 5;
  int c = blockIdx.x * 32 + tx;
  for (int i = 0; i < 32; i += 8) {
    int r = blockIdx.y * 32 + ty + i;
    tile[ty + i][tx] = f2bf(in[(size_t)r * C + c]);
  }
  __syncthreads();
  int r = blockIdx.y * 32 + tx;
  for (int i = 0; i < 32; i += 8) {
    int cc = blockIdx.x * 32 + ty + i;
    out[(size_t)cc * R + r] = tile[tx][ty + i];
  }
}

// ---------------- bf16 MFMA GEMM: C[M][N] = A[M][K] * BT[N][K]^T + bias ----------------
__global__ __launch_bounds__(256) void k_gemm_bt(const u16* __restrict__ A,
                                                 const u16* __restrict__ BT,
                                                 const float* __restrict__ bias,
                                                 float* __restrict__ C,
                                                 int M, int N, int K) {
  __shared__ u16 As[128][40];
  __shared__ u16 Bs[128][40];
  const int m0 = blockIdx.y * 128, n0 = blockIdx.x * 128;
  const int tid = threadIdx.x;
  const int lane = tid & 63, wave = tid >> 6;
  const int wm = (wave >> 1) * 64, wn = (wave & 1) * 64;
  const int lm = lane & 15, quad = lane >> 4;
  const int r = tid >> 1, kh = (tid & 1) * 16;

  f32x4 acc[4][4];
  for (int i = 0; i < 4; i++)
    for (int j = 0; j < 4; j++) acc[i][j] = (f32x4){0.f, 0.f, 0.f, 0.f};

  for (int k0 = 0; k0 < K; k0 += 32) {
    const uint4* ap = (const uint4*)(A + (size_t)(m0 + r) * K + k0 + kh);
    uint4 av0 = ap[0], av1 = ap[1];
    const uint4* bp = (const uint4*)(BT + (size_t)(n0 + r) * K + k0 + kh);
    uint4 bv0 = bp[0], bv1 = bp[1];
    __syncthreads();
    *(uint4*)&As[r][kh] = av0; *(uint4*)&As[r][kh + 8] = av1;
    *(uint4*)&Bs[r][kh] = bv0; *(uint4*)&Bs[r][kh + 8] = bv1;
    __syncthreads();
    bf16x8 a_frag[4], b_frag[4];
    for (int i = 0; i < 4; i++) a_frag[i] = *(const bf16x8*)&As[wm + i * 16 + lm][quad * 8];
    for (int j = 0; j < 4; j++) b_frag[j] = *(const bf16x8*)&Bs[wn + j * 16 + lm][quad * 8];
    for (int i = 0; i < 4; i++)
      for (int j = 0; j < 4; j++)
        acc[i][j] = __builtin_amdgcn_mfma_f32_16x16x32_bf16(a_frag[i], b_frag[j], acc[i][j], 0, 0, 0);
  }
  for (int i = 0; i < 4; i++)
    for (int j = 0; j < 4; j++) {
      int row = m0 + wm + i * 16 + quad * 4;
      int col = n0 + wn + j * 16 + lm;
      float bc = bias[col];
      for (int rr = 0; rr < 4; rr++)
        C[(size_t)(row + rr) * N + col] = acc[i][j][rr] + bc;
    }
}

// ---------------- persistent LSTM scan: sentinel-sync, Wh in LDS ----------------
// 128 WGs x 256 thr (1 WG/CU). WG g owns h-cols [8g,8g+8) x 4 gates (32 packed cols).
// h(t) lives in per-step slot t of hseq (sentinel-cleared). Producers fire-and-forget
// coherent u32 stores (the data IS the flag); consumers do a BULK coherent load of
// their A-fragments and retry only sentinel words. No plain loads of hseq ever (a
// too-early plain load would cache the sentinel in L2 forever - R5's regression).
// One __syncthreads per step (z_buf parity handles WAR).
__global__ __launch_bounds__(256, 1) void k_lstm(const float* __restrict__ Z,   // [8192][4096]
                                                 const u16* __restrict__ WhT,   // [4096][1024]
                                                 const float* __restrict__ c0,  // [32][1024]
                                                 u16* __restrict__ hseq,        // [257][32][1024]
                                                 u16* __restrict__ Hs,          // [8192][1024]
                                                 float* __restrict__ out_c,
                                                 float* __restrict__ out_h) {
  __shared__ u16 Whs[32][1032];           // 32 packed cols x K=1024 (+8 pad) = 66 KB
  __shared__ float z_buf[2][2][32][34];   // [t-parity][khalf][batch][packed col]
  const int g = blockIdx.x;
  const int tid = threadIdx.x;
  const int lane = tid & 63, wave = tid >> 6;
  const int lm = lane & 15, quad = lane >> 4;
  const int mhalf = wave & 1, khalf = wave >> 1;
  const int b = tid >> 3, jl = tid & 7;

  // stage Wh^T slice into LDS: packed col pc -> WhT row (pc>>3)*1024 + 8g + (pc&7)
  {
    int pc = tid >> 3, seg = tid & 7;
    int grow = (pc >> 3) * 1024 + 8 * g + (pc & 7);
    const uint4* src = (const uint4*)(WhT + (size_t)grow * 1024 + seg * 128);
#pragma unroll
    for (int i = 0; i < 16; i++) {
      uint4 v = src[i];
      *(uint4*)&Whs[pc][seg * 128 + i * 8] = v;
    }
  }
  float creg = c0[b * 1024 + 8 * g + jl];
  __syncthreads();   // Whs ready before first MFMA

  // per-lane A-fragment base: batch row mhalf*16+lm, k base khalf*512+quad*8
  // (mhalf x khalf tiling covers the 64 KB h exactly once per WG, no duplication)
  const size_t aoff = (size_t)(mhalf * 16 + lm) * 1024 + khalf * 512 + quad * 8;

  for (int t = 0; t < 256; t++) {
    // Z prefetch (plain loads, LLC-cached; overlaps the h wait)
    size_t zbase = ((size_t)b * 256 + t) * 4096 + 8 * g + jl;
    float z_i = Z[zbase], z_f = Z[zbase + 1024], z_g = Z[zbase + 2048], z_o = Z[zbase + 3072];

    // A-fragments: bulk coherent load (all 32 u64s issued back-to-back, pipelined)
    const u16* hp = hseq + (size_t)t * 32768 + aoff;
    union { u64 q[2]; bf16x8 v; } fr[16];
#pragma unroll
    for (int i = 0; i < 16; i++) {
      const u64* qp = (const u64*)(hp + i * 32);
      fr[i].q[0] = __hip_atomic_load(qp,     __ATOMIC_RELAXED, __HIP_MEMORY_SCOPE_AGENT);
      fr[i].q[1] = __hip_atomic_load(qp + 1, __ATOMIC_RELAXED, __HIP_MEMORY_SCOPE_AGENT);
    }
    // sentinel retry: bulk rounds, only stale words re-issued (masked)
    while (true) {
      int bad = 0;
#pragma unroll
      for (int i = 0; i < 16; i++) {
        const u64* qp = (const u64*)(hp + i * 32);
        if (badw(fr[i].q[0])) { fr[i].q[0] = __hip_atomic_load(qp,     __ATOMIC_RELAXED, __HIP_MEMORY_SCOPE_AGENT); bad = 1; }
        if (badw(fr[i].q[1])) { fr[i].q[1] = __hip_atomic_load(qp + 1, __ATOMIC_RELAXED, __HIP_MEMORY_SCOPE_AGENT); bad = 1; }
      }
      if (!__any(bad)) break;
      __builtin_amdgcn_s_sleep(1);
    }

    // MFMA: 2 ntiles x 16 ks, 4 independent chains; B-frags from LDS
    f32x4 a0e = (f32x4){0.f, 0.f, 0.f, 0.f}, a0o = a0e, a1e = a0e, a1o = a0e;
    const int kb = khalf * 512 + quad * 8;
#pragma unroll
    for (int ks = 0; ks < 16; ks += 2) {
      bf16x8 b0e = *(const bf16x8*)&Whs[lm][kb + ks * 32];
      bf16x8 b1e = *(const bf16x8*)&Whs[16 + lm][kb + ks * 32];
      bf16x8 b0o = *(const bf16x8*)&Whs[lm][kb + (ks + 1) * 32];
      bf16x8 b1o = *(const bf16x8*)&Whs[16 + lm][kb + (ks + 1) * 32];
      a0e = __builtin_amdgcn_mfma_f32_16x16x32_bf16(fr[ks].v,     b0e, a0e, 0, 0, 0);
      a1e = __builtin_amdgcn_mfma_f32_16x16x32_bf16(fr[ks].v,     b1e, a1e, 0, 0, 0);
      a0o = __builtin_amdgcn_mfma_f32_16x16x32_bf16(fr[ks + 1].v, b0o, a0o, 0, 0, 0);
      a1o = __builtin_amdgcn_mfma_f32_16x16x32_bf16(fr[ks + 1].v, b1o, a1o, 0, 0, 0);
    }
    f32x4 zt0 = a0e + a0o, zt1 = a1e + a1o;
    const int par = t & 1;
    for (int rr = 0; rr < 4; rr++) {
      z_buf[par][khalf][mhalf * 16 + quad * 4 + rr][lm]      = zt0[rr];
      z_buf[par][khalf][mhalf * 16 + quad * 4 + rr][16 + lm] = zt1[rr];
    }
    __syncthreads();   // the ONLY barrier per step

    // gates: one (b, col) per thread
    float zi = z_buf[par][0][b][jl]      + z_buf[par][1][b][jl]      + z_i;
    float zf = z_buf[par][0][b][8 + jl]  + z_buf[par][1][b][8 + jl]  + z_f;
    float zg = z_buf[par][0][b][16 + jl] + z_buf[par][1][b][16 + jl] + z_g;
    float zo = z_buf[par][0][b][24 + jl] + z_buf[par][1][b][24 + jl] + z_o;
    float ig = sigm(zi), fg = sigm(zf), gg = tanh_fast(zg), og = sigm(zo);
    creg = fg * creg + ig * gg;
    float hv = og * tanh_fast(creg);
    u32 hw = (u32)f2bf(hv);
    u32 nb = (u32)__shfl_xor((int)hw, 1);   // partner col (same wave, same b)
    if ((jl & 1) == 0) {
      u32 word = hw | (nb << 16);
      // fire-and-forget coherent store: the data IS the flag
      __hip_atomic_store((u32*)(hseq + (size_t)(t + 1) * 32768 + b * 1024 + 8 * g + jl),
                         word, __ATOMIC_RELAXED, __HIP_MEMORY_SCOPE_AGENT);
      __builtin_nontemporal_store(word, (u32*)(Hs + ((size_t)b * 256 + t) * 1024 + 8 * g + jl));
    }
    if (t == 255) {
      out_c[b * 1024 + 8 * g + jl] = creg;
      out_h[b * 1024 + 8 * g + jl] = hv;
    }
  }
}

extern "C" void kernel_launch(void* const* d_in, const int* in_sizes, int n_in,
                              void* d_out, int out_size, void* d_ws, size_t ws_size,
                              hipStream_t stream) {
  const float* c0   = (const float*)d_in[0];
  const float* h0   = (const float*)d_in[1];
  const float* X    = (const float*)d_in[2];   // [32,256,1024]
  const float* Wi   = (const float*)d_in[3];   // [1024][4096]
  const float* Wh   = (const float*)d_in[4];   // [1024][4096]
  const float* bias = (const float*)d_in[5];   // [4096]
  const float* Wd   = (const float*)d_in[6];   // [1024][1024]
  const float* bd   = (const float*)d_in[7];   // [1024]
  float* out   = (float*)d_out;
  float* out_c = out;
  float* out_h = out + 32768;
  float* out_x = out + 65536;

  char* ws = (char*)d_ws;
  size_t off = 0;
  auto alloc = [&](size_t bytes) { char* p = ws + off; off += (bytes + 255) & ~255ull; return p; };
  float* Z   = (float*)alloc(134217728ull);   // [8192][4096] fp32
  u16*   Xb  = (u16*)alloc(16777216ull);      // [8192][1024] bf16 (dead after GEMM1)
  u16*   WiT = (u16*)alloc(8388608ull);       // [4096][1024] bf16 (dead after GEMM1)
  u16*   WhT = (u16*)alloc(8388608ull);       // [4096][1024] bf16
  u16*   WdT = (u16*)alloc(2097152ull);       // [1024][1024] bf16
  u16*   Hs  = (u16*)alloc(16777216ull);      // [8192][1024] bf16
  // hseq [257][32768] u16 = 16.84 MB aliases the dead Xb+WiT region (25 MB)
  u16*   hseq = Xb;
  const int hseq_u16 = 257 * 32768;
  if (off > ws_size) {
    fprintf(stderr, "WS too small: need %zu have %zu\n", off, ws_size);
    return;
  }

  k_convert<<<2048, 256, 0, stream>>>(X, Xb, 8388608 / 4);
  k_transpose<<<dim3(128, 32), 256, 0, stream>>>(Wi, WiT, 1024, 4096);
  k_transpose<<<dim3(128, 32), 256, 0, stream>>>(Wh, WhT, 1024, 4096);
  k_transpose<<<dim3(32, 32), 256, 0, stream>>>(Wd, WdT, 1024, 1024);
  k_gemm_bt<<<dim3(32, 64), 256, 0, stream>>>(Xb, WiT, bias, Z, 8192, 4096, 1024);
  // Xb/WiT now dead: repurpose as hseq
  k_clear<<<2048, 256, 0, stream>>>((uint4*)hseq, hseq_u16 / 8);
  k_init_h<<<128, 256, 0, stream>>>(h0, hseq);
  k_lstm<<<NWG, 256, 0, stream>>>(Z, WhT, c0, hseq, Hs, out_c, out_h);
  k_gemm_bt<<<dim3(8, 64), 256, 0, stream>>>(Hs, WdT, bd, out_x, 8192, 1024, 1024);
}

// Round 7
// 1387.761 us; speedup vs baseline: 1.5441x; 1.5441x over previous
//
#include <hip/hip_runtime.h>
#include <cstdio>

typedef unsigned short u16;
typedef unsigned int u32;
typedef unsigned long long u64;
typedef __attribute__((ext_vector_type(8))) short bf16x8;   // 8 x bf16 (4 VGPRs)
typedef __attribute__((ext_vector_type(4))) float f32x4;

#define NWG 128
#define FLAG_STRIDE 32   // u32s -> 128 B between flags (own cacheline each)

__device__ inline u16 f2bf(float x) {
  union { float f; unsigned u; } v; v.f = x;
  unsigned r = v.u + 0x7FFFu + ((v.u >> 16) & 1u);   // RNE
  return (u16)(r >> 16);
}
__device__ inline float sigm(float x) { return 1.0f / (1.0f + __expf(-x)); }
__device__ inline float tanh_fast(float x) { return 1.0f - 2.0f / (__expf(2.0f * x) + 1.0f); }

// ---------------- fp32 -> bf16 convert (vectorized) ----------------
__global__ __launch_bounds__(256) void k_convert(const float* __restrict__ in,
                                                 u16* __restrict__ out, int n4) {
  int i = blockIdx.x * blockDim.x + threadIdx.x;
  int stride = gridDim.x * blockDim.x;
  const float4* in4 = (const float4*)in;
  ushort4* out4 = (ushort4*)out;
  for (; i < n4; i += stride) {
    float4 v = in4[i];
    ushort4 o; o.x = f2bf(v.x); o.y = f2bf(v.y); o.z = f2bf(v.z); o.w = f2bf(v.w);
    out4[i] = o;
  }
}

// h0 -> hseq slot 0 (bf16), zero the per-WG flags
__global__ __launch_bounds__(256) void k_init_h(const float* __restrict__ h0,
                                                u16* __restrict__ hseq,
                                                u32* __restrict__ flags) {
  int i = blockIdx.x * blockDim.x + threadIdx.x;
  if (i < NWG * FLAG_STRIDE) flags[i] = 0u;
  if (i < 32768) hseq[i] = f2bf(h0[i]);
}

// [R][C] fp32 -> [C][R] bf16 (tiled transpose)
__global__ __launch_bounds__(256) void k_transpose(const float* __restrict__ in,
                                                   u16* __restrict__ out, int R, int C) {
  __shared__ u16 tile[32][33];
  int tx = threadIdx.x & 31, ty = threadIdx.x >> 5;
  int c = blockIdx.x * 32 + tx;
  for (int i = 0; i < 32; i += 8) {
    int r = blockIdx.y * 32 + ty + i;
    tile[ty + i][tx] = f2bf(in[(size_t)r * C + c]);
  }
  __syncthreads();
  int r = blockIdx.y * 32 + tx;
  for (int i = 0; i < 32; i += 8) {
    int cc = blockIdx.x * 32 + ty + i;
    out[(size_t)cc * R + r] = tile[tx][ty + i];
  }
}

// ---------------- bf16 MFMA GEMM: C[M][N] = A[M][K] * BT[N][K]^T + bias ----------------
__global__ __launch_bounds__(256) void k_gemm_bt(const u16* __restrict__ A,
                                                 const u16* __restrict__ BT,
                                                 const float* __restrict__ bias,
                                                 float* __restrict__ C,
                                                 int M, int N, int K) {
  __shared__ u16 As[128][40];
  __shared__ u16 Bs[128][40];
  const int m0 = blockIdx.y * 128, n0 = blockIdx.x * 128;
  const int tid = threadIdx.x;
  const int lane = tid & 63, wave = tid >> 6;
  const int wm = (wave >> 1) * 64, wn = (wave & 1) * 64;
  const int lm = lane & 15, quad = lane >> 4;
  const int r = tid >> 1, kh = (tid & 1) * 16;

  f32x4 acc[4][4];
  for (int i = 0; i < 4; i++)
    for (int j = 0; j < 4; j++) acc[i][j] = (f32x4){0.f, 0.f, 0.f, 0.f};

  for (int k0 = 0; k0 < K; k0 += 32) {
    const uint4* ap = (const uint4*)(A + (size_t)(m0 + r) * K + k0 + kh);
    uint4 av0 = ap[0], av1 = ap[1];
    const uint4* bp = (const uint4*)(BT + (size_t)(n0 + r) * K + k0 + kh);
    uint4 bv0 = bp[0], bv1 = bp[1];
    __syncthreads();
    *(uint4*)&As[r][kh] = av0; *(uint4*)&As[r][kh + 8] = av1;
    *(uint4*)&Bs[r][kh] = bv0; *(uint4*)&Bs[r][kh + 8] = bv1;
    __syncthreads();
    bf16x8 a_frag[4], b_frag[4];
    for (int i = 0; i < 4; i++) a_frag[i] = *(const bf16x8*)&As[wm + i * 16 + lm][quad * 8];
    for (int j = 0; j < 4; j++) b_frag[j] = *(const bf16x8*)&Bs[wn + j * 16 + lm][quad * 8];
    for (int i = 0; i < 4; i++)
      for (int j = 0; j < 4; j++)
        acc[i][j] = __builtin_amdgcn_mfma_f32_16x16x32_bf16(a_frag[i], b_frag[j], acc[i][j], 0, 0, 0);
  }
  for (int i = 0; i < 4; i++)
    for (int j = 0; j < 4; j++) {
      int row = m0 + wm + i * 16 + quad * 4;
      int col = n0 + wn + j * 16 + lm;
      float bc = bias[col];
      for (int rr = 0; rr < 4; rr++)
        C[(size_t)(row + rr) * N + col] = acc[i][j][rr] + bc;
    }
}

// ---------------- persistent LSTM scan: flags + L2-amortized plain h loads ----------------
// 128 WGs x 256 thr (1 WG/CU). WG g owns h-cols [8g,8g+8) x 4 gates (32 packed cols).
// Producer: coherent packed-u32 h stores -> __syncthreads (vmcnt0 drain) -> flag store.
// Consumer: poll all 128 flags, then PLAIN (L2-cached) h loads. Safe: post-flag the
// slot is complete at LLC and no XCD L2 holds a stale copy (producers bypass L2 via
// sc0sc1; no consumer touches the line pre-flag; kernel-boundary inv cleared aliases).
// The 8 WGs per XCD share one L2 fetch of each h line -> 8x less LLC traffic than
// all-coherent staging (R3), no sentinel retry storms (R5/R6).
__global__ __launch_bounds__(256, 1) void k_lstm(const float* __restrict__ Z,   // [8192][4096]
                                                 const u16* __restrict__ WhT,   // [4096][1024]
                                                 const float* __restrict__ c0,  // [32][1024]
                                                 u16* __restrict__ hseq,        // [257][32][1024]
                                                 u16* __restrict__ Hs,          // [8192][1024]
                                                 float* __restrict__ out_c,
                                                 float* __restrict__ out_h,
                                                 u32* __restrict__ flags) {
  __shared__ u16 Whs[32][1032];           // 32 packed cols x K=1024 (+8 pad) = 66 KB
  __shared__ float z_buf[2][2][32][34];   // [t-parity][khalf][batch][packed col]
  const int g = blockIdx.x;
  const int tid = threadIdx.x;
  const int lane = tid & 63, wave = tid >> 6;
  const int lm = lane & 15, quad = lane >> 4;
  const int mhalf = wave & 1, khalf = wave >> 1;
  const int b = tid >> 3, jl = tid & 7;

  // stage Wh^T slice into LDS: packed col pc -> WhT row (pc>>3)*1024 + 8g + (pc&7)
  {
    int pc = tid >> 3, seg = tid & 7;
    int grow = (pc >> 3) * 1024 + 8 * g + (pc & 7);
    const uint4* src = (const uint4*)(WhT + (size_t)grow * 1024 + seg * 128);
#pragma unroll
    for (int i = 0; i < 16; i++) {
      uint4 v = src[i];
      *(uint4*)&Whs[pc][seg * 128 + i * 8] = v;
    }
  }
  float creg = c0[b * 1024 + 8 * g + jl];
  __syncthreads();   // Whs ready before first MFMA

  // per-lane A-fragment base: batch row mhalf*16+lm, k base khalf*512+quad*8
  // (mhalf x khalf tiling covers the 64 KB h exactly once per WG, no duplication)
  const size_t aoff = (size_t)(mhalf * 16 + lm) * 1024 + khalf * 512 + quad * 8;

  for (int t = 0; t < 256; t++) {
    // Z prefetch (cold HBM, ~900 cyc - overlaps the flag poll)
    size_t zbase = ((size_t)b * 256 + t) * 4096 + 8 * g + jl;
    float z_i = Z[zbase], z_f = Z[zbase + 1024], z_g = Z[zbase + 2048], z_o = Z[zbase + 3072];

    // flag poll: every wave checks all 128 flags (2 per lane), coherent loads
    {
      const u32 tgt = (u32)t;
      const u32* f0 = flags + lane * FLAG_STRIDE;
      const u32* f1 = flags + (lane + 64) * FLAG_STRIDE;
      while (true) {
        u32 v0 = __hip_atomic_load(f0, __ATOMIC_RELAXED, __HIP_MEMORY_SCOPE_AGENT);
        u32 v1 = __hip_atomic_load(f1, __ATOMIC_RELAXED, __HIP_MEMORY_SCOPE_AGENT);
        if (__all((v0 >= tgt) && (v1 >= tgt))) break;
        __builtin_amdgcn_s_sleep(1);
      }
      asm volatile("" ::: "memory");  // keep h loads below the poll
    }

    // A-fragments: PLAIN vector loads (L2-amortized across the XCD's 8 WGs)
    const u16* hp = hseq + (size_t)t * 32768 + aoff;
    bf16x8 fr[16];
#pragma unroll
    for (int i = 0; i < 16; i++) fr[i] = *(const bf16x8*)(hp + i * 32);

    // MFMA: 2 ntiles x 16 ks, 4 independent chains; B-frags from LDS
    f32x4 a0e = (f32x4){0.f, 0.f, 0.f, 0.f}, a0o = a0e, a1e = a0e, a1o = a0e;
    const int kb = khalf * 512 + quad * 8;
#pragma unroll
    for (int ks = 0; ks < 16; ks += 2) {
      bf16x8 b0e = *(const bf16x8*)&Whs[lm][kb + ks * 32];
      bf16x8 b1e = *(const bf16x8*)&Whs[16 + lm][kb + ks * 32];
      bf16x8 b0o = *(const bf16x8*)&Whs[lm][kb + (ks + 1) * 32];
      bf16x8 b1o = *(const bf16x8*)&Whs[16 + lm][kb + (ks + 1) * 32];
      a0e = __builtin_amdgcn_mfma_f32_16x16x32_bf16(fr[ks],     b0e, a0e, 0, 0, 0);
      a1e = __builtin_amdgcn_mfma_f32_16x16x32_bf16(fr[ks],     b1e, a1e, 0, 0, 0);
      a0o = __builtin_amdgcn_mfma_f32_16x16x32_bf16(fr[ks + 1], b0o, a0o, 0, 0, 0);
      a1o = __builtin_amdgcn_mfma_f32_16x16x32_bf16(fr[ks + 1], b1o, a1o, 0, 0, 0);
    }
    f32x4 zt0 = a0e + a0o, zt1 = a1e + a1o;
    const int par = t & 1;
    for (int rr = 0; rr < 4; rr++) {
      z_buf[par][khalf][mhalf * 16 + quad * 4 + rr][lm]      = zt0[rr];
      z_buf[par][khalf][mhalf * 16 + quad * 4 + rr][16 + lm] = zt1[rr];
    }
    __syncthreads();   // B2: z_buf ready

    // gates: one (b, col) per thread
    float zi = z_buf[par][0][b][jl]      + z_buf[par][1][b][jl]      + z_i;
    float zf = z_buf[par][0][b][8 + jl]  + z_buf[par][1][b][8 + jl]  + z_f;
    float zg = z_buf[par][0][b][16 + jl] + z_buf[par][1][b][16 + jl] + z_g;
    float zo = z_buf[par][0][b][24 + jl] + z_buf[par][1][b][24 + jl] + z_o;
    float ig = sigm(zi), fg = sigm(zf), gg = tanh_fast(zg), og = sigm(zo);
    creg = fg * creg + ig * gg;
    float hv = og * tanh_fast(creg);
    u32 hw = (u32)f2bf(hv);
    u32 nb = (u32)__shfl_xor((int)hw, 1);   // partner col (same wave, same b)
    if ((jl & 1) == 0) {
      u32 word = hw | (nb << 16);
      // coherent store: lands at LLC (bypasses L2) -> visible to all XCDs post-flag
      __hip_atomic_store((u32*)(hseq + (size_t)(t + 1) * 32768 + b * 1024 + 8 * g + jl),
                         word, __ATOMIC_RELAXED, __HIP_MEMORY_SCOPE_AGENT);
      __builtin_nontemporal_store(word, (u32*)(Hs + ((size_t)b * 256 + t) * 1024 + 8 * g + jl));
    }
    if (t == 255) {
      out_c[b * 1024 + 8 * g + jl] = creg;
      out_h[b * 1024 + 8 * g + jl] = hv;
    }
    __syncthreads();   // B3: per-thread vmcnt(0) -> all h stores at the LLC
    if (tid == 0)
      __hip_atomic_store(flags + g * FLAG_STRIDE, (u32)(t + 1),
                         __ATOMIC_RELAXED, __HIP_MEMORY_SCOPE_AGENT);
  }
}

extern "C" void kernel_launch(void* const* d_in, const int* in_sizes, int n_in,
                              void* d_out, int out_size, void* d_ws, size_t ws_size,
                              hipStream_t stream) {
  const float* c0   = (const float*)d_in[0];
  const float* h0   = (const float*)d_in[1];
  const float* X    = (const float*)d_in[2];   // [32,256,1024]
  const float* Wi   = (const float*)d_in[3];   // [1024][4096]
  const float* Wh   = (const float*)d_in[4];   // [1024][4096]
  const float* bias = (const float*)d_in[5];   // [4096]
  const float* Wd   = (const float*)d_in[6];   // [1024][1024]
  const float* bd   = (const float*)d_in[7];   // [1024]
  float* out   = (float*)d_out;
  float* out_c = out;
  float* out_h = out + 32768;
  float* out_x = out + 65536;

  char* ws = (char*)d_ws;
  size_t off = 0;
  auto alloc = [&](size_t bytes) { char* p = ws + off; off += (bytes + 255) & ~255ull; return p; };
  float* Z   = (float*)alloc(134217728ull);   // [8192][4096] fp32
  u16*   Xb  = (u16*)alloc(16777216ull);      // [8192][1024] bf16 (dead after GEMM1)
  u16*   WiT = (u16*)alloc(8388608ull);       // [4096][1024] bf16 (dead after GEMM1)
  u16*   WhT = (u16*)alloc(8388608ull);       // [4096][1024] bf16
  u16*   WdT = (u16*)alloc(2097152ull);       // [1024][1024] bf16
  u16*   Hs  = (u16*)alloc(16777216ull);      // [8192][1024] bf16
  u32*   flags = (u32*)alloc(NWG * FLAG_STRIDE * 4);
  // hseq [257][32768] u16 = 16.84 MB aliases the dead Xb+WiT region (25 MB);
  // no sentinel clear needed: flags gate every read.
  u16*   hseq = Xb;
  if (off > ws_size) {
    fprintf(stderr, "WS too small: need %zu have %zu\n", off, ws_size);
    return;
  }

  k_convert<<<2048, 256, 0, stream>>>(X, Xb, 8388608 / 4);
  k_transpose<<<dim3(128, 32), 256, 0, stream>>>(Wi, WiT, 1024, 4096);
  k_transpose<<<dim3(128, 32), 256, 0, stream>>>(Wh, WhT, 1024, 4096);
  k_transpose<<<dim3(32, 32), 256, 0, stream>>>(Wd, WdT, 1024, 1024);
  k_gemm_bt<<<dim3(32, 64), 256, 0, stream>>>(Xb, WiT, bias, Z, 8192, 4096, 1024);
  // Xb/WiT now dead: repurpose as hseq (slot 0 = h0, written below)
  k_init_h<<<128, 256, 0, stream>>>(h0, hseq, flags);
  k_lstm<<<NWG, 256, 0, stream>>>(Z, WhT, c0, hseq, Hs, out_c, out_h, flags);
  k_gemm_bt<<<dim3(8, 64), 256, 0, stream>>>(Hs, WdT, bd, out_x, 8192, 1024, 1024);
}